// Round 1
// 395.354 us; speedup vs baseline: 1.2049x; 1.2049x over previous
//
#include <hip/hip_runtime.h>

#define NFEAT 256
#define GS 32
#define NG 8
#define BATCH 32
#define HW 4096
#define NTOT (BATCH*HW)   // 131072 samples per channel
#define EPSV 1e-5f

// ws layout (float offsets)
#define RPART_SZ (NG*64*1024)                 // 524288 floats
#define SPART_OFF (RPART_SZ)                  // 8*64*32 = 16384
#define WMT_OFF   (SPART_OFF + NG*64*32)      // 8*1024
#define BETA_OFF  (WMT_OFF + NG*1024)         // 8*32

// ---------------------------------------------------------------------------
// Kernel 1: per-(g,b,half) partial raw gram R = X X^T and channel sums S.
// R2 fix: the old acc[4][32] (128 VGPRs) forced the compiler to cap at 128
// regs and spill the accumulator -> WRITE_SIZE 328 MB of scratch, 237us.
// New decomposition: 64 threads = 8x8 grid of 4x4 tiles (16 acc regs).
// The 4 waves split the 2048-sample window 4 ways; cross-wave reduce via LDS.
// Inner loop: 8 float4 loads -> 64 statically-indexed FMAs; ~100 VGPRs.
// Row+col loads per iter touch the same 32 cache lines -> L1 merges the
// 8x logical re-read; HBM fetch stays ~134 MB.
// ---------------------------------------------------------------------------
__global__ __launch_bounds__(256, 2) void dbn_stats(const float* __restrict__ x,
                                                    float* __restrict__ Rpart,
                                                    float* __restrict__ Spart) {
    int bx = blockIdx.x;            // 0..511
    int g  = bx >> 6;
    int pb = bx & 63;               // b*2 + h
    int b  = pb >> 1, h = pb & 1;
    int tid = threadIdx.x;
    int w  = tid >> 6;              // wave 0..3 (sample-split)
    int t  = tid & 63;
    int tr = t >> 3, tc = t & 7;    // 8x8 tile grid; tile = 4 rows x 4 cols

    const float* xg = x + ((size_t)(b*NFEAT + g*GS))*HW + h*2048 + w*512;
    const float* rp0 = xg + (size_t)(tr*4)*HW;
    const float* cp0 = xg + (size_t)(tc*4)*HW;

    float acc[4][4];
    float srow[4];
    #pragma unroll
    for (int i = 0; i < 4; ++i) {
        srow[i] = 0.f;
        #pragma unroll
        for (int j = 0; j < 4; ++j) acc[i][j] = 0.f;
    }

    #pragma unroll 2
    for (int it = 0; it < 128; ++it) {   // 512 samples / 4 per float4
        int s = it*4;
        float4 ra[4], cb[4];
        #pragma unroll
        for (int i = 0; i < 4; ++i) ra[i] = *(const float4*)(rp0 + (size_t)i*HW + s);
        #pragma unroll
        for (int j = 0; j < 4; ++j) cb[j] = *(const float4*)(cp0 + (size_t)j*HW + s);

        #pragma unroll
        for (int i = 0; i < 4; ++i) {
            #pragma unroll
            for (int j = 0; j < 4; ++j) {
                float a = acc[i][j];
                a = fmaf(ra[i].x, cb[j].x, a);
                a = fmaf(ra[i].y, cb[j].y, a);
                a = fmaf(ra[i].z, cb[j].z, a);
                a = fmaf(ra[i].w, cb[j].w, a);
                acc[i][j] = a;
            }
            srow[i] += (ra[i].x + ra[i].y) + (ra[i].z + ra[i].w);
        }
    }

    // cross-wave reduction via LDS (epilogue, once per block)
    __shared__ float red[4][64][16];   // 16 KB
    __shared__ float sred[4][8][4];    // 512 B
    #pragma unroll
    for (int i = 0; i < 4; ++i)
        #pragma unroll
        for (int j = 0; j < 4; ++j)
            red[w][t][i*4 + j] = acc[i][j];
    if (tc == 0) {
        #pragma unroll
        for (int i = 0; i < 4; ++i) sred[w][tr][i] = srow[i];
    }
    __syncthreads();

    float* Rp = Rpart + (size_t)(g*64 + pb)*1024;
    #pragma unroll
    for (int q = 0; q < 4; ++q) {
        int e = tid + 256*q;         // coalesced global write
        int c = e >> 5, d = e & 31;
        int tile = (c >> 2)*8 + (d >> 2);
        int slot = (c & 3)*4 + (d & 3);
        Rp[e] = red[0][tile][slot] + red[1][tile][slot]
              + red[2][tile][slot] + red[3][tile][slot];
    }
    if (tid < 32) {
        int c = tid;
        Spart[(size_t)(g*64 + pb)*32 + c] =
            sred[0][c>>2][c&3] + sred[1][c>>2][c&3]
          + sred[2][c>>2][c&3] + sred[3][c>>2][c&3];
    }
}

// ---------------------------------------------------------------------------
// Kernel 2: per-group solver. R2: 1024 threads (1 gram entry per thread)
// instead of 256x4 -> 4x the TLP for the 64-partial reduce and the LDS
// Newton-Schulz matmuls (this kernel runs on only 8 CUs).
// ---------------------------------------------------------------------------
__global__ __launch_bounds__(1024) void dbn_solver(const float* __restrict__ Rpart, const float* __restrict__ Spart,
                           const float* __restrict__ weight, const float* __restrict__ bias,
                           float* __restrict__ wmT, float* __restrict__ beta) {
    __shared__ float Y[1024], Z[1024], T[1024], S[32], M[32];
    __shared__ float sh_s;
    int g = blockIdx.x;
    int tid = threadIdx.x;
    int c = tid >> 5, d = tid & 31;

    if (tid < 32) {
        float s = 0.f;
        for (int pb = 0; pb < 64; ++pb) s += Spart[(size_t)(g*64 + pb)*32 + tid];
        S[tid] = s;
        M[tid] = s / (float)NTOT;
    }
    float rs = 0.f;
    for (int pb = 0; pb < 64; ++pb) rs += Rpart[(size_t)(g*64 + pb)*1024 + tid];
    __syncthreads();

    const float invN = 1.0f/(float)NTOT;
    float v = rs - S[c]*S[d]*invN;
    if (c == d) v += EPSV;
    T[tid] = v;
    __syncthreads();

    if (tid == 0) {
        float tr = 0.f;
        for (int k = 0; k < 32; ++k) tr += T[k*33];
        sh_s = tr / 32.0f;
    }
    __syncthreads();
    float sc = sh_s;
    float invs = 1.0f / sc;

    Y[tid] = v * invs;
    Z[tid] = (c == d) ? 1.0f : 0.0f;
    __syncthreads();

    for (int it = 0; it < 8; ++it) {
        float s2 = 0.f;
        #pragma unroll
        for (int k = 0; k < 32; ++k) s2 = fmaf(Z[c*32 + k], Y[k*32 + d], s2);
        float a = ((c == d) ? 3.0f : 0.0f) - s2;
        __syncthreads();
        T[tid] = a;
        __syncthreads();
        float sy = 0.f, sz = 0.f;
        #pragma unroll
        for (int k = 0; k < 32; ++k) {
            sy = fmaf(Y[c*32 + k], T[k*32 + d], sy);
            sz = fmaf(T[c*32 + k], Z[k*32 + d], sz);
        }
        __syncthreads();
        Y[tid] = 0.5f*sy;
        Z[tid] = 0.5f*sz;
        __syncthreads();
    }

    float wfac = rsqrtf(sc);   // sigma^{-1/2} = Z / sqrt(s)
    wmT[(size_t)g*1024 + d*32 + c] = Z[tid]*wfac*weight[g*GS + c];  // transposed + weight-folded
    if (tid < 32) {
        float s2 = 0.f;
        #pragma unroll
        for (int k = 0; k < 32; ++k) s2 = fmaf(Z[tid*32 + k], M[k], s2);
        beta[g*GS + tid] = -s2*wfac*weight[g*GS + tid] + bias[g*GS + tid];
    }
}

// ---------------------------------------------------------------------------
// Kernel 3: whiten. out[c] = sum_d wmT[d][c] * x[d] + beta[c].
// One thread per spatial position; wm/beta indices are wave-uniform -> s_load,
// inner loop is pure v_fmac(v, s, v). Memory-bound: 134 MB in + 134 MB out.
// (Unchanged this round — no counters for it yet; it will surface in the
// top-5 once dbn_stats drops to ~30us.)
// ---------------------------------------------------------------------------
__global__ __launch_bounds__(256) void dbn_whiten(const float* __restrict__ x,
                                                  const float* __restrict__ wmT,
                                                  const float* __restrict__ beta,
                                                  float* __restrict__ out) {
    int bx = blockIdx.x;            // 0..4095
    int gb = bx >> 4;               // 0..255
    int chunk = bx & 15;
    int b = gb >> 3, g = gb & 7;
    size_t base = ((size_t)(b*NFEAT + g*GS))*HW + chunk*256 + threadIdx.x;
    const float* wg = wmT + (size_t)g*1024;
    const float* bg = beta + (size_t)g*GS;

    float v[32];
    #pragma unroll
    for (int d = 0; d < 32; ++d) v[d] = x[base + (size_t)d*HW];

    float acc[32];
    #pragma unroll
    for (int c = 0; c < 32; ++c) acc[c] = bg[c];

    #pragma unroll
    for (int d = 0; d < 32; ++d) {
        float vd = v[d];
        #pragma unroll
        for (int c = 0; c < 32; ++c) acc[c] = fmaf(wg[d*32 + c], vd, acc[c]);
    }

    #pragma unroll
    for (int c = 0; c < 32; ++c) out[base + (size_t)c*HW] = acc[c];
}

extern "C" void kernel_launch(void* const* d_in, const int* in_sizes, int n_in,
                              void* d_out, int out_size, void* d_ws, size_t ws_size,
                              hipStream_t stream) {
    const float* x      = (const float*)d_in[0];
    const float* weight = (const float*)d_in[1];
    const float* bias   = (const float*)d_in[2];
    float* out = (float*)d_out;
    float* ws  = (float*)d_ws;

    float* Rpart = ws;
    float* Spart = ws + SPART_OFF;
    float* wmT   = ws + WMT_OFF;
    float* beta  = ws + BETA_OFF;

    dbn_stats <<<512, 256, 0, stream>>>(x, Rpart, Spart);
    dbn_solver<<<NG, 1024, 0, stream>>>(Rpart, Spart, weight, bias, wmT, beta);
    dbn_whiten<<<4096, 256, 0, stream>>>(x, wmT, beta, out);
}